// Round 2
// baseline (545.893 us; speedup 1.0000x reference)
//
#include <hip/hip_runtime.h>

#define N_NODES 50000
#define N_EDGES 800000
#define N_LABEL 200000
#define HID 64

// ---------------- ws layout (4-byte units) ----------------
static const size_t OFF_W1C  = 0;                                   // 64*64
static const size_t OFF_B1C  = 4096;                                // 64
static const size_t OFF_CE   = 4160;                                // 2
static const size_t OFF_H    = 4224;                                // 50000*64
static const size_t OFF_AGG  = OFF_H    + (size_t)N_NODES * HID;    // 50000*64
static const size_t OFF_ASRC = OFF_AGG  + (size_t)N_NODES * HID;    // 50000
static const size_t OFF_ADST = OFF_ASRC + (size_t)N_NODES;          // 50000
static const size_t OFF_ROW  = OFF_ADST + (size_t)N_NODES;          // 50001 (int)
static const size_t OFF_CNT  = OFF_ROW  + (size_t)N_NODES + 1;      // 50000 (int)
static const size_t OFF_SRCP = OFF_CNT  + (size_t)N_NODES;          // 800000 (int)
static const size_t OFF_EAP  = OFF_SRCP + (size_t)N_EDGES;          // 800000 (float)
// total = 8,204,225 * 4B ~= 32.8 MB

// Fold author linear into GAT1 weight; compute per-edge-attr scalar coefs.
__global__ void prep_kernel(const float* __restrict__ Wa, const float* __restrict__ ba,
                            const float* __restrict__ c1W,
                            const float* __restrict__ c1We, const float* __restrict__ c1ae,
                            const float* __restrict__ c2We, const float* __restrict__ c2ae,
                            float* __restrict__ W1c, float* __restrict__ b1c,
                            float* __restrict__ ce) {
    int t = threadIdx.x;
    for (int idx = t; idx < 64 * 64; idx += 256) {
        int i = idx >> 6, j = idx & 63;
        float s = 0.f;
        for (int k = 0; k < 64; ++k) s += Wa[i * 64 + k] * c1W[k * 64 + j];
        W1c[idx] = s;
    }
    if (t < 64) {
        float s = 0.f;
        for (int k = 0; k < 64; ++k) s += ba[k] * c1W[k * 64 + t];
        b1c[t] = s;
    }
    if (t == 64) {
        float s = 0.f;
        for (int k = 0; k < 64; ++k) s += c1We[k] * c1ae[k];
        ce[0] = s;
    }
    if (t == 65) {
        float s = 0.f;
        for (int k = 0; k < 64; ++k) s += c2We[k] * c2ae[k];
        ce[1] = s;
    }
}

// ---------------- CSR build ----------------
__global__ void hist_kernel(const int* __restrict__ ei, int* __restrict__ cnt) {
    int e = blockIdx.x * blockDim.x + threadIdx.x;
    if (e < N_EDGES) atomicAdd(&cnt[ei[N_EDGES + e]], 1);
}

// one block, 1024 threads: exclusive scan of cnt[50000] -> row_ptr[50001]
__global__ void scan_kernel(const int* __restrict__ cnt, int* __restrict__ row_ptr) {
    __shared__ int sums[1024];
    const int CH = 49;  // 1024*49 = 50176 >= 50000
    int t = threadIdx.x;
    int beg = t * CH, end = min(beg + CH, N_NODES);
    int own = 0;
    for (int i = beg; i < end; ++i) own += cnt[i];
    sums[t] = own;
    __syncthreads();
    for (int off = 1; off < 1024; off <<= 1) {
        int v = (t >= off) ? sums[t - off] : 0;
        __syncthreads();
        sums[t] += v;
        __syncthreads();
    }
    int base = sums[t] - own;  // exclusive prefix for this thread's chunk
    for (int i = beg; i < end; ++i) { row_ptr[i] = base; base += cnt[i]; }
    if (t == 1023) row_ptr[N_NODES] = sums[1023];
}

// scatter edges into CSR order; consumes cnt (ends at zero)
__global__ void scatter_kernel(const int* __restrict__ ei, const float* __restrict__ ea,
                               const int* __restrict__ row_ptr, int* __restrict__ cnt,
                               int* __restrict__ srcp, float* __restrict__ eap) {
    int e = blockIdx.x * blockDim.x + threadIdx.x;
    if (e >= N_EDGES) return;
    int d = ei[N_EDGES + e];
    int old = atomicSub(&cnt[d], 1);           // old in [1..deg]
    int pos = row_ptr[d] + old - 1;
    srcp[pos] = ei[e];
    eap[pos]  = ea[e];
}

// H = act(X + preb) @ W + postb ; Asrc = H . avs ; Adst = H . avd
__global__ void gemm_attn_kernel(const float* __restrict__ X,
                                 const float* __restrict__ preb, int do_relu,
                                 const float* __restrict__ W,
                                 const float* __restrict__ postb,
                                 const float* __restrict__ avs,
                                 const float* __restrict__ avd,
                                 float* __restrict__ H,
                                 float* __restrict__ Asrc, float* __restrict__ Adst,
                                 int n) {
    __shared__ float Wl[64 * 64];
    int t = threadIdx.x;
    for (int i = t; i < 64 * 64; i += 256) Wl[i] = W[i];
    __syncthreads();
    int lane = t & 63;
    int wid  = t >> 6;
    float as_l = avs[lane], ad_l = avd[lane];
    float pb = preb  ? preb[lane]  : 0.f;
    float ob = postb ? postb[lane] : 0.f;
    for (int row = blockIdx.x * 4 + wid; row < n; row += gridDim.x * 4) {
        float xv = X[(size_t)row * 64 + lane] + pb;
        if (do_relu) xv = fmaxf(xv, 0.f);
        float acc = 0.f;
#pragma unroll
        for (int k = 0; k < 64; ++k)
            acc += __shfl(xv, k) * Wl[k * 64 + lane];
        float h = acc + ob;
        H[(size_t)row * 64 + lane] = h;
        float s1 = h * as_l, s2 = h * ad_l;
#pragma unroll
        for (int off = 32; off > 0; off >>= 1) {
            s1 += __shfl_xor(s1, off);
            s2 += __shfl_xor(s2, off);
        }
        if (lane == 0) { Asrc[row] = s1; Adst[row] = s2; }
    }
}

// Fused per-dst gather: alpha -> exp -> weighted sum -> normalize. No atomics.
__global__ void aggregate_csr_kernel(const int* __restrict__ row_ptr,
                                     const int* __restrict__ srcp,
                                     const float* __restrict__ eap,
                                     const float* __restrict__ Asrc,
                                     const float* __restrict__ Adst,
                                     const float* __restrict__ cep,
                                     const float* __restrict__ H,
                                     float* __restrict__ Agg) {
    int lane = threadIdx.x & 63;
    int wid  = threadIdx.x >> 6;
    int node = blockIdx.x * 4 + wid;
    if (node >= N_NODES) return;
    float ce = *cep;
    float ad = Adst[node];
    int beg = row_ptr[node], end = row_ptr[node + 1];
    float acc = 0.f, accp = 0.f;
    int pos = beg;
    if (pos < end) {
        int   s  = srcp[pos];
        float ev = eap[pos];
        for (;;) {
            float as_ = Asrc[s];
            float hv  = H[(size_t)s * 64 + lane];
            ++pos;
            int   s2 = 0; float ev2 = 0.f;
            bool more = pos < end;
            if (more) { s2 = srcp[pos]; ev2 = eap[pos]; }  // prefetch next scalars
            float al = as_ + ad + ev * ce;
            al = al >= 0.f ? al : 0.2f * al;
            float p = __expf(al);
            acc  += p * hv;
            accp += p;
            if (!more) break;
            s = s2; ev = ev2;
        }
    }
    Agg[(size_t)node * 64 + lane] = acc / (accp + 1e-16f);
}

// Edge classifier: out[e] = dot(Agg[i]+b, Agg[j]+b). Quarter-wave per edge, float4.
__global__ void classify_kernel(const int* __restrict__ eli,
                                const float* __restrict__ Agg,
                                const float* __restrict__ bias,
                                float* __restrict__ out) {
    int t    = threadIdx.x;
    int q    = t & 15;                       // lane within 16-lane group
    int grp  = (blockIdx.x * blockDim.x + t) >> 4;  // global 16-lane group id
    if (grp >= N_LABEL) return;
    int e = grp;
    const float4* b4p = (const float4*)bias;
    float4 b = b4p[q & 15];
    int i = eli[e], j = eli[N_LABEL + e];
    const float4* Ai = (const float4*)(Agg + (size_t)i * 64);
    const float4* Aj = (const float4*)(Agg + (size_t)j * 64);
    float4 a = Ai[q], c = Aj[q];
    float s = (a.x + b.x) * (c.x + b.x) + (a.y + b.y) * (c.y + b.y) +
              (a.z + b.z) * (c.z + b.z) + (a.w + b.w) * (c.w + b.w);
#pragma unroll
    for (int off = 8; off > 0; off >>= 1) s += __shfl_xor(s, off);
    if (q == 0) out[e] = s;
}

extern "C" void kernel_launch(void* const* d_in, const int* in_sizes, int n_in,
                              void* d_out, int out_size, void* d_ws, size_t ws_size,
                              hipStream_t stream) {
    const float* x    = (const float*)d_in[0];
    const float* ea   = (const float*)d_in[1];
    const float* Wa   = (const float*)d_in[2];
    const float* ba   = (const float*)d_in[3];
    const float* c1W  = (const float*)d_in[4];
    const float* c1as = (const float*)d_in[5];
    const float* c1ad = (const float*)d_in[6];
    const float* c1We = (const float*)d_in[7];
    const float* c1ae = (const float*)d_in[8];
    const float* c1b  = (const float*)d_in[9];
    const float* c2W  = (const float*)d_in[10];
    const float* c2as = (const float*)d_in[11];
    const float* c2ad = (const float*)d_in[12];
    const float* c2We = (const float*)d_in[13];
    const float* c2ae = (const float*)d_in[14];
    const float* c2b  = (const float*)d_in[15];
    const int*   ei   = (const int*)d_in[16];
    const int*   eli  = (const int*)d_in[17];
    float* out = (float*)d_out;

    float* w    = (float*)d_ws;
    float* W1c  = w + OFF_W1C;
    float* b1c  = w + OFF_B1C;
    float* ce   = w + OFF_CE;
    float* H    = w + OFF_H;
    float* Agg  = w + OFF_AGG;
    float* Asrc = w + OFF_ASRC;
    float* Adst = w + OFF_ADST;
    int*   rowp = (int*)(w + OFF_ROW);
    int*   cnt  = (int*)(w + OFF_CNT);
    int*   srcp = (int*)(w + OFF_SRCP);
    float* eap  = w + OFF_EAP;

    // ---- prep + CSR build (structure shared by both layers) ----
    prep_kernel<<<1, 256, 0, stream>>>(Wa, ba, c1W, c1We, c1ae, c2We, c2ae,
                                       W1c, b1c, ce);
    hipMemsetAsync(cnt, 0, (size_t)N_NODES * sizeof(int), stream);
    hist_kernel<<<(N_EDGES + 255) / 256, 256, 0, stream>>>(ei, cnt);
    scan_kernel<<<1, 1024, 0, stream>>>(cnt, rowp);
    scatter_kernel<<<(N_EDGES + 255) / 256, 256, 0, stream>>>(ei, ea, rowp, cnt,
                                                              srcp, eap);

    // ---- layer 1 ----
    gemm_attn_kernel<<<12500, 256, 0, stream>>>(x, nullptr, 0, W1c, b1c,
                                                c1as, c1ad, H, Asrc, Adst, N_NODES);
    aggregate_csr_kernel<<<12500, 256, 0, stream>>>(rowp, srcp, eap, Asrc, Adst,
                                                    ce + 0, H, Agg);

    // ---- layer 2 ----
    gemm_attn_kernel<<<12500, 256, 0, stream>>>(Agg, c1b, 1, c2W, nullptr,
                                                c2as, c2ad, H, Asrc, Adst, N_NODES);
    aggregate_csr_kernel<<<12500, 256, 0, stream>>>(rowp, srcp, eap, Asrc, Adst,
                                                    ce + 1, H, Agg);

    // ---- classifier ----
    classify_kernel<<<(N_LABEL * 16 + 255) / 256, 256, 0, stream>>>(eli, Agg, c2b, out);
}

// Round 6
// 432.216 us; speedup vs baseline: 1.2630x; 1.2630x over previous
//
#include <hip/hip_runtime.h>

#define N_NODES 50000
#define N_EDGES 800000
#define N_LABEL 200000
#define HID 64
#define SCAN_BLOCKS 196   // ceil(50000/256)

// ---------------- ws layout (4-byte units) ----------------
static const size_t OFF_W1C  = 0;                                   // 64*64
static const size_t OFF_B1C  = 4096;                                // 64
static const size_t OFF_CE   = 4160;                                // 2
static const size_t OFF_H    = 4224;                                // 50000*64
static const size_t OFF_AGG  = OFF_H    + (size_t)N_NODES * HID;    // 50000*64
static const size_t OFF_ASRC = OFF_AGG  + (size_t)N_NODES * HID;    // 50000
static const size_t OFF_ADST = OFF_ASRC + (size_t)N_NODES;          // 50000
static const size_t OFF_ROW  = OFF_ADST + (size_t)N_NODES;          // 50002 (int, padded)
static const size_t OFF_CNT  = OFF_ROW  + (size_t)N_NODES + 2;      // 50000 (int)
static const size_t OFF_PACK = OFF_CNT  + (size_t)N_NODES;          // 2*800000 (int2), 8B-aligned
static const size_t OFF_BSUM = OFF_PACK + 2 * (size_t)N_EDGES;      // 256 (int)
// total ~= 33 MB

// Fold author linear into GAT1 weight; compute per-edge-attr scalar coefs.
__global__ void prep_kernel(const float* __restrict__ Wa, const float* __restrict__ ba,
                            const float* __restrict__ c1W,
                            const float* __restrict__ c1We, const float* __restrict__ c1ae,
                            const float* __restrict__ c2We, const float* __restrict__ c2ae,
                            float* __restrict__ W1c, float* __restrict__ b1c,
                            float* __restrict__ ce) {
    int t = threadIdx.x;
    for (int idx = t; idx < 64 * 64; idx += 256) {
        int i = idx >> 6, j = idx & 63;
        float s = 0.f;
        for (int k = 0; k < 64; ++k) s += Wa[i * 64 + k] * c1W[k * 64 + j];
        W1c[idx] = s;
    }
    if (t < 64) {
        float s = 0.f;
        for (int k = 0; k < 64; ++k) s += ba[k] * c1W[k * 64 + t];
        b1c[t] = s;
    }
    if (t == 64) {
        float s = 0.f;
        for (int k = 0; k < 64; ++k) s += c1We[k] * c1ae[k];
        ce[0] = s;
    }
    if (t == 65) {
        float s = 0.f;
        for (int k = 0; k < 64; ++k) s += c2We[k] * c2ae[k];
        ce[1] = s;
    }
}

// ---------------- CSR build ----------------
__global__ void hist_kernel(const int* __restrict__ ei, int* __restrict__ cnt) {
    int e = blockIdx.x * blockDim.x + threadIdx.x;
    if (e < N_EDGES) atomicAdd(&cnt[ei[N_EDGES + e]], 1);
}

// Parallel scan, phase A: per-block (256-wide) sums.
__global__ void block_sum_kernel(const int* __restrict__ cnt, int* __restrict__ bsum) {
    __shared__ int red[256];
    int t = threadIdx.x;
    int i = blockIdx.x * 256 + t;
    red[t] = (i < N_NODES) ? cnt[i] : 0;
    __syncthreads();
    for (int off = 128; off > 0; off >>= 1) {
        if (t < off) red[t] += red[t + off];
        __syncthreads();
    }
    if (t == 0) bsum[blockIdx.x] = red[0];
}

// Phase B: one block scans the 196 block sums -> exclusive bases (in place).
__global__ void scan_bsum_kernel(int* __restrict__ bsum) {
    __shared__ int s[256];
    int t = threadIdx.x;
    int v = (t < SCAN_BLOCKS) ? bsum[t] : 0;
    s[t] = v;
    __syncthreads();
    for (int off = 1; off < 256; off <<= 1) {
        int u = (t >= off) ? s[t - off] : 0;
        __syncthreads();
        s[t] += u;
        __syncthreads();
    }
    if (t < SCAN_BLOCKS) bsum[t] = s[t] - v;   // exclusive base
}

// Phase C: per-block inclusive scan + base -> exclusive row_ptr.
__global__ void scan_final_kernel(const int* __restrict__ cnt,
                                  const int* __restrict__ bsum,
                                  int* __restrict__ row_ptr) {
    __shared__ int s[256];
    int t = threadIdx.x;
    int i = blockIdx.x * 256 + t;
    int v = (i < N_NODES) ? cnt[i] : 0;
    s[t] = v;
    __syncthreads();
    for (int off = 1; off < 256; off <<= 1) {
        int u = (t >= off) ? s[t - off] : 0;
        __syncthreads();
        s[t] += u;
        __syncthreads();
    }
    int excl = s[t] - v + bsum[blockIdx.x];
    if (i < N_NODES) row_ptr[i] = excl;
    if (i == N_NODES - 1) row_ptr[N_NODES] = excl + v;
}

// scatter edges into CSR order (packed {src, edge_attr}); consumes cnt.
__global__ void scatter_kernel(const int* __restrict__ ei, const float* __restrict__ ea,
                               const int* __restrict__ row_ptr, int* __restrict__ cnt,
                               int2* __restrict__ pack) {
    int e = blockIdx.x * blockDim.x + threadIdx.x;
    if (e >= N_EDGES) return;
    int d = ei[N_EDGES + e];
    int old = atomicSub(&cnt[d], 1);           // old in [1..deg]
    int pos = row_ptr[d] + old - 1;
    int2 pr; pr.x = ei[e]; pr.y = __float_as_int(ea[e]);
    pack[pos] = pr;
}

// H = act(X + preb) @ W + postb ; Asrc = H . avs ; Adst = H . avd
__global__ void gemm_attn_kernel(const float* __restrict__ X,
                                 const float* __restrict__ preb, int do_relu,
                                 const float* __restrict__ W,
                                 const float* __restrict__ postb,
                                 const float* __restrict__ avs,
                                 const float* __restrict__ avd,
                                 float* __restrict__ H,
                                 float* __restrict__ Asrc, float* __restrict__ Adst,
                                 int n) {
    __shared__ float Wl[64 * 64];
    int t = threadIdx.x;
    for (int i = t; i < 64 * 64; i += 256) Wl[i] = W[i];
    __syncthreads();
    int lane = t & 63;
    int wid  = t >> 6;
    float as_l = avs[lane], ad_l = avd[lane];
    float pb = preb  ? preb[lane]  : 0.f;
    float ob = postb ? postb[lane] : 0.f;
    for (int row = blockIdx.x * 4 + wid; row < n; row += gridDim.x * 4) {
        float xv = X[(size_t)row * 64 + lane] + pb;
        if (do_relu) xv = fmaxf(xv, 0.f);
        float acc = 0.f;
#pragma unroll
        for (int k = 0; k < 64; ++k)
            acc += __shfl(xv, k) * Wl[k * 64 + lane];
        float h = acc + ob;
        H[(size_t)row * 64 + lane] = h;
        float s1 = h * as_l, s2 = h * ad_l;
#pragma unroll
        for (int off = 32; off > 0; off >>= 1) {
            s1 += __shfl_xor(s1, off);
            s2 += __shfl_xor(s2, off);
        }
        if (lane == 0) { Asrc[row] = s1; Adst[row] = s2; }
    }
}

// Fused per-dst gather: alpha -> exp -> weighted sum -> normalize. No atomics.
// One wave per node: lane = 4 edge-subgroups x 16 feature-lanes (float4 each).
__global__ void aggregate_csr_kernel(const int* __restrict__ row_ptr,
                                     const int2* __restrict__ pack,
                                     const float* __restrict__ Asrc,
                                     const float* __restrict__ Adst,
                                     const float* __restrict__ cep,
                                     const float* __restrict__ H,
                                     float* __restrict__ Agg) {
    int t    = threadIdx.x;
    int q    = t & 15;          // feature quad (16 lanes x float4 = 64 feats)
    int sub  = (t >> 4) & 3;    // edge subgroup 0..3
    int wid  = t >> 6;          // wave in block
    int node = blockIdx.x * 4 + wid;
    if (node >= N_NODES) return;
    float ce = *cep;
    float ad = Adst[node];
    int beg = row_ptr[node], end = row_ptr[node + 1];
    float ax = 0.f, ay = 0.f, az = 0.f, aw = 0.f, accp = 0.f;
    for (int pos = beg + sub; pos < end; pos += 4) {
        int2  pr  = pack[pos];
        int   s   = pr.x;
        float ev  = __int_as_float(pr.y);
        float as_ = Asrc[s];
        float4 hv = *(const float4*)(H + (size_t)s * 64 + q * 4);
        float al = as_ + ad + ev * ce;
        al = al >= 0.f ? al : 0.2f * al;
        float p = __expf(al);
        ax += p * hv.x; ay += p * hv.y; az += p * hv.z; aw += p * hv.w;
        accp += p;
    }
    // reduce across the 4 edge-subgroups (lane = sub*16 + q): xor 16 then 32
    ax += __shfl_xor(ax, 16); ax += __shfl_xor(ax, 32);
    ay += __shfl_xor(ay, 16); ay += __shfl_xor(ay, 32);
    az += __shfl_xor(az, 16); az += __shfl_xor(az, 32);
    aw += __shfl_xor(aw, 16); aw += __shfl_xor(aw, 32);
    accp += __shfl_xor(accp, 16); accp += __shfl_xor(accp, 32);
    if (sub == 0) {
        float inv = 1.f / (accp + 1e-16f);
        float4 o; o.x = ax * inv; o.y = ay * inv; o.z = az * inv; o.w = aw * inv;
        *(float4*)(Agg + (size_t)node * 64 + q * 4) = o;
    }
}

// Edge classifier: out[e] = dot(Agg[i]+b, Agg[j]+b). 16-lane group per edge, float4.
__global__ void classify_kernel(const int* __restrict__ eli,
                                const float* __restrict__ Agg,
                                const float* __restrict__ bias,
                                float* __restrict__ out) {
    int t    = threadIdx.x;
    int q    = t & 15;
    int grp  = (blockIdx.x * blockDim.x + t) >> 4;
    if (grp >= N_LABEL) return;
    int e = grp;
    float4 b = ((const float4*)bias)[q];
    int i = eli[e], j = eli[N_LABEL + e];
    float4 a = ((const float4*)(Agg + (size_t)i * 64))[q];
    float4 c = ((const float4*)(Agg + (size_t)j * 64))[q];
    float s = (a.x + b.x) * (c.x + b.x) + (a.y + b.y) * (c.y + b.y) +
              (a.z + b.z) * (c.z + b.z) + (a.w + b.w) * (c.w + b.w);
#pragma unroll
    for (int off = 8; off > 0; off >>= 1) s += __shfl_xor(s, off);
    if (q == 0) out[e] = s;
}

extern "C" void kernel_launch(void* const* d_in, const int* in_sizes, int n_in,
                              void* d_out, int out_size, void* d_ws, size_t ws_size,
                              hipStream_t stream) {
    const float* x    = (const float*)d_in[0];
    const float* ea   = (const float*)d_in[1];
    const float* Wa   = (const float*)d_in[2];
    const float* ba   = (const float*)d_in[3];
    const float* c1W  = (const float*)d_in[4];
    const float* c1as = (const float*)d_in[5];
    const float* c1ad = (const float*)d_in[6];
    const float* c1We = (const float*)d_in[7];
    const float* c1ae = (const float*)d_in[8];
    const float* c1b  = (const float*)d_in[9];
    const float* c2W  = (const float*)d_in[10];
    const float* c2as = (const float*)d_in[11];
    const float* c2ad = (const float*)d_in[12];
    const float* c2We = (const float*)d_in[13];
    const float* c2ae = (const float*)d_in[14];
    const float* c2b  = (const float*)d_in[15];
    const int*   ei   = (const int*)d_in[16];
    const int*   eli  = (const int*)d_in[17];
    float* out = (float*)d_out;

    float* w    = (float*)d_ws;
    float* W1c  = w + OFF_W1C;
    float* b1c  = w + OFF_B1C;
    float* ce   = w + OFF_CE;
    float* H    = w + OFF_H;
    float* Agg  = w + OFF_AGG;
    float* Asrc = w + OFF_ASRC;
    float* Adst = w + OFF_ADST;
    int*   rowp = (int*)(w + OFF_ROW);
    int*   cnt  = (int*)(w + OFF_CNT);
    int2*  pack = (int2*)(w + OFF_PACK);
    int*   bsum = (int*)(w + OFF_BSUM);

    // ---- prep + CSR build (structure shared by both layers) ----
    prep_kernel<<<1, 256, 0, stream>>>(Wa, ba, c1W, c1We, c1ae, c2We, c2ae,
                                       W1c, b1c, ce);
    hipMemsetAsync(cnt, 0, (size_t)N_NODES * sizeof(int), stream);
    hist_kernel<<<(N_EDGES + 255) / 256, 256, 0, stream>>>(ei, cnt);
    block_sum_kernel<<<SCAN_BLOCKS, 256, 0, stream>>>(cnt, bsum);
    scan_bsum_kernel<<<1, 256, 0, stream>>>(bsum);
    scan_final_kernel<<<SCAN_BLOCKS, 256, 0, stream>>>(cnt, bsum, rowp);
    scatter_kernel<<<(N_EDGES + 255) / 256, 256, 0, stream>>>(ei, ea, rowp, cnt, pack);

    // ---- layer 1 ----
    gemm_attn_kernel<<<12500, 256, 0, stream>>>(x, nullptr, 0, W1c, b1c,
                                                c1as, c1ad, H, Asrc, Adst, N_NODES);
    aggregate_csr_kernel<<<12500, 256, 0, stream>>>(rowp, pack, Asrc, Adst,
                                                    ce + 0, H, Agg);

    // ---- layer 2 ----
    gemm_attn_kernel<<<12500, 256, 0, stream>>>(Agg, c1b, 1, c2W, nullptr,
                                                c2as, c2ad, H, Asrc, Adst, N_NODES);
    aggregate_csr_kernel<<<12500, 256, 0, stream>>>(rowp, pack, Asrc, Adst,
                                                    ce + 1, H, Agg);

    // ---- classifier ----
    classify_kernel<<<(N_LABEL * 16 + 255) / 256, 256, 0, stream>>>(eli, Agg, c2b, out);
}

// Round 8
// 337.018 us; speedup vs baseline: 1.6198x; 1.2825x over previous
//
#include <hip/hip_runtime.h>

#define N_NODES 50000
#define N_EDGES 800000
#define N_LABEL 200000
#define HID 64
#define SCAN_BLOCKS 196   // ceil(50000/256)

// ---------------- ws layout (4-byte units) ----------------
static const size_t OFF_W1C  = 0;                                   // 64*64
static const size_t OFF_B1C  = 4096;                                // 64
static const size_t OFF_CE   = 4160;                                // 2
static const size_t OFF_H    = 4224;                                // 50000*64
static const size_t OFF_AGG  = OFF_H    + (size_t)N_NODES * HID;    // 50000*64
static const size_t OFF_ASRC = OFF_AGG  + (size_t)N_NODES * HID;    // 50000
static const size_t OFF_ADST = OFF_ASRC + (size_t)N_NODES;          // 50000
static const size_t OFF_ROW  = OFF_ADST + (size_t)N_NODES;          // 50002 (int, padded)
static const size_t OFF_CNT  = OFF_ROW  + (size_t)N_NODES + 2;      // 50000 (int)
static const size_t OFF_PACK = OFF_CNT  + (size_t)N_NODES;          // 2*800000 (int2), 8B-aligned
static const size_t OFF_BSUM = OFF_PACK + 2 * (size_t)N_EDGES;      // 256 (int)
// total ~= 33 MB

// Fold author linear into GAT1 weight; compute per-edge-attr scalar coefs.
__global__ void prep_kernel(const float* __restrict__ Wa, const float* __restrict__ ba,
                            const float* __restrict__ c1W,
                            const float* __restrict__ c1We, const float* __restrict__ c1ae,
                            const float* __restrict__ c2We, const float* __restrict__ c2ae,
                            float* __restrict__ W1c, float* __restrict__ b1c,
                            float* __restrict__ ce) {
    int t = threadIdx.x;
    for (int idx = t; idx < 64 * 64; idx += 256) {
        int i = idx >> 6, j = idx & 63;
        float s = 0.f;
        for (int k = 0; k < 64; ++k) s += Wa[i * 64 + k] * c1W[k * 64 + j];
        W1c[idx] = s;
    }
    if (t < 64) {
        float s = 0.f;
        for (int k = 0; k < 64; ++k) s += ba[k] * c1W[k * 64 + t];
        b1c[t] = s;
    }
    if (t == 64) {
        float s = 0.f;
        for (int k = 0; k < 64; ++k) s += c1We[k] * c1ae[k];
        ce[0] = s;
    }
    if (t == 65) {
        float s = 0.f;
        for (int k = 0; k < 64; ++k) s += c2We[k] * c2ae[k];
        ce[1] = s;
    }
}

// ---------------- CSR build ----------------
__global__ void hist_kernel(const int* __restrict__ ei, int* __restrict__ cnt) {
    int e = blockIdx.x * blockDim.x + threadIdx.x;
    if (e < N_EDGES) atomicAdd(&cnt[ei[N_EDGES + e]], 1);
}

// Parallel scan, phase A: per-block (256-wide) sums.
__global__ void block_sum_kernel(const int* __restrict__ cnt, int* __restrict__ bsum) {
    __shared__ int red[256];
    int t = threadIdx.x;
    int i = blockIdx.x * 256 + t;
    red[t] = (i < N_NODES) ? cnt[i] : 0;
    __syncthreads();
    for (int off = 128; off > 0; off >>= 1) {
        if (t < off) red[t] += red[t + off];
        __syncthreads();
    }
    if (t == 0) bsum[blockIdx.x] = red[0];
}

// Phase B: one block scans the 196 block sums -> exclusive bases (in place).
__global__ void scan_bsum_kernel(int* __restrict__ bsum) {
    __shared__ int s[256];
    int t = threadIdx.x;
    int v = (t < SCAN_BLOCKS) ? bsum[t] : 0;
    s[t] = v;
    __syncthreads();
    for (int off = 1; off < 256; off <<= 1) {
        int u = (t >= off) ? s[t - off] : 0;
        __syncthreads();
        s[t] += u;
        __syncthreads();
    }
    if (t < SCAN_BLOCKS) bsum[t] = s[t] - v;   // exclusive base
}

// Phase C: per-block inclusive scan + base -> exclusive row_ptr.
__global__ void scan_final_kernel(const int* __restrict__ cnt,
                                  const int* __restrict__ bsum,
                                  int* __restrict__ row_ptr) {
    __shared__ int s[256];
    int t = threadIdx.x;
    int i = blockIdx.x * 256 + t;
    int v = (i < N_NODES) ? cnt[i] : 0;
    s[t] = v;
    __syncthreads();
    for (int off = 1; off < 256; off <<= 1) {
        int u = (t >= off) ? s[t - off] : 0;
        __syncthreads();
        s[t] += u;
        __syncthreads();
    }
    int excl = s[t] - v + bsum[blockIdx.x];
    if (i < N_NODES) row_ptr[i] = excl;
    if (i == N_NODES - 1) row_ptr[N_NODES] = excl + v;
}

// scatter edges into CSR order (packed {src, edge_attr}); consumes cnt.
__global__ void scatter_kernel(const int* __restrict__ ei, const float* __restrict__ ea,
                               const int* __restrict__ row_ptr, int* __restrict__ cnt,
                               int2* __restrict__ pack) {
    int e = blockIdx.x * blockDim.x + threadIdx.x;
    if (e >= N_EDGES) return;
    int d = ei[N_EDGES + e];
    int old = atomicSub(&cnt[d], 1);           // old in [1..deg]
    int pos = row_ptr[d] + old - 1;
    int2 pr; pr.x = ei[e]; pr.y = __float_as_int(ea[e]);
    pack[pos] = pr;
}

// H = X @ W (+postb) ; Asrc = H . avs ; Adst = H . avd
// W column held in 64 VGPRs per lane; X row loaded at wave-uniform addresses
// (row made uniform via readfirstlane) -> no LDS-pipe traffic in the K-loop.
__global__ void gemm_attn_kernel(const float* __restrict__ X,
                                 const float* __restrict__ W,
                                 const float* __restrict__ postb, int has_postb,
                                 const float* __restrict__ avs,
                                 const float* __restrict__ avd,
                                 float* __restrict__ H,
                                 float* __restrict__ Asrc, float* __restrict__ Adst) {
    int lane = threadIdx.x & 63;
    int wid  = __builtin_amdgcn_readfirstlane(threadIdx.x >> 6);  // uniform
    int gwave  = blockIdx.x * 4 + wid;
    int nwaves = gridDim.x * 4;
    // one-time: W column `lane` into registers
    float wcol[64];
#pragma unroll
    for (int k = 0; k < 64; ++k) wcol[k] = W[k * 64 + lane];
    float as_l = avs[lane], ad_l = avd[lane];
    float ob = has_postb ? postb[lane] : 0.f;
    for (int row = gwave; row < N_NODES; row += nwaves) {
        const float4* xr4 = (const float4*)(X + (size_t)row * 64);  // uniform addr
        float acc = ob;
#pragma unroll
        for (int i = 0; i < 16; ++i) {
            float4 xq = xr4[i];
            acc = fmaf(xq.x, wcol[4 * i + 0], acc);
            acc = fmaf(xq.y, wcol[4 * i + 1], acc);
            acc = fmaf(xq.z, wcol[4 * i + 2], acc);
            acc = fmaf(xq.w, wcol[4 * i + 3], acc);
        }
        H[(size_t)row * 64 + lane] = acc;
        float s1 = acc * as_l, s2 = acc * ad_l;
#pragma unroll
        for (int off = 32; off > 0; off >>= 1) {
            s1 += __shfl_xor(s1, off);
            s2 += __shfl_xor(s2, off);
        }
        if (lane == 0) { Asrc[row] = s1; Adst[row] = s2; }
    }
}

// Fused per-dst gather: alpha -> exp -> weighted sum -> normalize (+opt bias/relu).
// One wave per node: lane = 4 edge-subgroups x 16 feature-lanes (float4 each).
__global__ void aggregate_csr_kernel(const int* __restrict__ row_ptr,
                                     const int2* __restrict__ pack,
                                     const float* __restrict__ Asrc,
                                     const float* __restrict__ Adst,
                                     const float* __restrict__ cep,
                                     const float* __restrict__ H,
                                     float* __restrict__ Agg,
                                     const float* __restrict__ obias, int do_relu) {
    int t    = threadIdx.x;
    int q    = t & 15;          // feature quad (16 lanes x float4 = 64 feats)
    int sub  = (t >> 4) & 3;    // edge subgroup 0..3
    int wid  = t >> 6;          // wave in block
    int node = blockIdx.x * 4 + wid;
    if (node >= N_NODES) return;
    float ce = *cep;
    float ad = Adst[node];
    int beg = row_ptr[node], end = row_ptr[node + 1];
    float ax = 0.f, ay = 0.f, az = 0.f, aw = 0.f, accp = 0.f;
    for (int pos = beg + sub; pos < end; pos += 4) {
        int2  pr  = pack[pos];
        int   s   = pr.x;
        float ev  = __int_as_float(pr.y);
        float as_ = Asrc[s];
        float4 hv = *(const float4*)(H + (size_t)s * 64 + q * 4);
        float al = as_ + ad + ev * ce;
        al = al >= 0.f ? al : 0.2f * al;
        float p = __expf(al);
        ax += p * hv.x; ay += p * hv.y; az += p * hv.z; aw += p * hv.w;
        accp += p;
    }
    // reduce across the 4 edge-subgroups (lane = sub*16 + q): xor 16 then 32
    ax += __shfl_xor(ax, 16); ax += __shfl_xor(ax, 32);
    ay += __shfl_xor(ay, 16); ay += __shfl_xor(ay, 32);
    az += __shfl_xor(az, 16); az += __shfl_xor(az, 32);
    aw += __shfl_xor(aw, 16); aw += __shfl_xor(aw, 32);
    accp += __shfl_xor(accp, 16); accp += __shfl_xor(accp, 32);
    if (sub == 0) {
        float inv = 1.f / (accp + 1e-16f);
        float4 o; o.x = ax * inv; o.y = ay * inv; o.z = az * inv; o.w = aw * inv;
        if (obias) {
            float4 b = ((const float4*)obias)[q];
            o.x += b.x; o.y += b.y; o.z += b.z; o.w += b.w;
            if (do_relu) {
                o.x = fmaxf(o.x, 0.f); o.y = fmaxf(o.y, 0.f);
                o.z = fmaxf(o.z, 0.f); o.w = fmaxf(o.w, 0.f);
            }
        }
        *(float4*)(Agg + (size_t)node * 64 + q * 4) = o;
    }
}

// Edge classifier: out[e] = dot(Agg[i]+b, Agg[j]+b). 16-lane group per edge, float4.
__global__ void classify_kernel(const int* __restrict__ eli,
                                const float* __restrict__ Agg,
                                const float* __restrict__ bias,
                                float* __restrict__ out) {
    int t    = threadIdx.x;
    int q    = t & 15;
    int grp  = (blockIdx.x * blockDim.x + t) >> 4;
    if (grp >= N_LABEL) return;
    int e = grp;
    float4 b = ((const float4*)bias)[q];
    int i = eli[e], j = eli[N_LABEL + e];
    float4 a = ((const float4*)(Agg + (size_t)i * 64))[q];
    float4 c = ((const float4*)(Agg + (size_t)j * 64))[q];
    float s = (a.x + b.x) * (c.x + b.x) + (a.y + b.y) * (c.y + b.y) +
              (a.z + b.z) * (c.z + b.z) + (a.w + b.w) * (c.w + b.w);
#pragma unroll
    for (int off = 8; off > 0; off >>= 1) s += __shfl_xor(s, off);
    if (q == 0) out[e] = s;
}

extern "C" void kernel_launch(void* const* d_in, const int* in_sizes, int n_in,
                              void* d_out, int out_size, void* d_ws, size_t ws_size,
                              hipStream_t stream) {
    const float* x    = (const float*)d_in[0];
    const float* ea   = (const float*)d_in[1];
    const float* Wa   = (const float*)d_in[2];
    const float* ba   = (const float*)d_in[3];
    const float* c1W  = (const float*)d_in[4];
    const float* c1as = (const float*)d_in[5];
    const float* c1ad = (const float*)d_in[6];
    const float* c1We = (const float*)d_in[7];
    const float* c1ae = (const float*)d_in[8];
    const float* c1b  = (const float*)d_in[9];
    const float* c2W  = (const float*)d_in[10];
    const float* c2as = (const float*)d_in[11];
    const float* c2ad = (const float*)d_in[12];
    const float* c2We = (const float*)d_in[13];
    const float* c2ae = (const float*)d_in[14];
    const float* c2b  = (const float*)d_in[15];
    const int*   ei   = (const int*)d_in[16];
    const int*   eli  = (const int*)d_in[17];
    float* out = (float*)d_out;

    float* w    = (float*)d_ws;
    float* W1c  = w + OFF_W1C;
    float* b1c  = w + OFF_B1C;
    float* ce   = w + OFF_CE;
    float* H    = w + OFF_H;
    float* Agg  = w + OFF_AGG;
    float* Asrc = w + OFF_ASRC;
    float* Adst = w + OFF_ADST;
    int*   rowp = (int*)(w + OFF_ROW);
    int*   cnt  = (int*)(w + OFF_CNT);
    int2*  pack = (int2*)(w + OFF_PACK);
    int*   bsum = (int*)(w + OFF_BSUM);

    // ---- prep + CSR build (structure shared by both layers) ----
    prep_kernel<<<1, 256, 0, stream>>>(Wa, ba, c1W, c1We, c1ae, c2We, c2ae,
                                       W1c, b1c, ce);
    hipMemsetAsync(cnt, 0, (size_t)N_NODES * sizeof(int), stream);
    hist_kernel<<<(N_EDGES + 255) / 256, 256, 0, stream>>>(ei, cnt);
    block_sum_kernel<<<SCAN_BLOCKS, 256, 0, stream>>>(cnt, bsum);
    scan_bsum_kernel<<<1, 256, 0, stream>>>(bsum);
    scan_final_kernel<<<SCAN_BLOCKS, 256, 0, stream>>>(cnt, bsum, rowp);
    scatter_kernel<<<(N_EDGES + 255) / 256, 256, 0, stream>>>(ei, ea, rowp, cnt, pack);

    // ---- layer 1: H1 = x @ W1c + b1c ; agg1 = softmax-agg(H1) + c1b, relu ----
    gemm_attn_kernel<<<1024, 256, 0, stream>>>(x, W1c, b1c, 1,
                                               c1as, c1ad, H, Asrc, Adst);
    aggregate_csr_kernel<<<12500, 256, 0, stream>>>(rowp, pack, Asrc, Adst,
                                                    ce + 0, H, Agg, c1b, 1);

    // ---- layer 2: H2 = agg1 @ c2W ; agg2 = softmax-agg(H2) ----
    gemm_attn_kernel<<<1024, 256, 0, stream>>>(Agg, c2W, nullptr, 0,
                                               c2as, c2ad, H, Asrc, Adst);
    aggregate_csr_kernel<<<12500, 256, 0, stream>>>(rowp, pack, Asrc, Adst,
                                                    ce + 1, H, Agg, nullptr, 0);

    // ---- classifier (adds c2b to both operands) ----
    classify_kernel<<<(N_LABEL * 16 + 255) / 256, 256, 0, stream>>>(eli, Agg, c2b, out);
}